// Round 1
// baseline (422.033 us; speedup 1.0000x reference)
//
#include <hip/hip_runtime.h>
#include <cstddef>
#include <stdint.h>

#define L_ 8192
#define BH_ 64
#define SCALE 0.1051120519067143f
#define SLD 72   // LDS row stride in ushorts (144 B): keeps ds_read_b128 16B-aligned
#define NY 16    // l-splits for the KV partial buffers

typedef __attribute__((ext_vector_type(8))) short bf16x8;
typedef __attribute__((ext_vector_type(4))) float f32x4;
typedef __attribute__((ext_vector_type(4))) unsigned short u16x4;

__device__ __forceinline__ float elu1(float x) {
    return x > 0.0f ? (x + 1.0f) : __expf(x);
}
__device__ __forceinline__ unsigned short f2bf(float x) {
    unsigned u = __float_as_uint(x);
    u += 0x7fffu + ((u >> 16) & 1u);
    return (unsigned short)(u >> 16);
}

// ---------------------------------------------------------------------------
// Zero the KV buffer (atomic fallback path only): 64*64*64 floats = 65536 f4
// ---------------------------------------------------------------------------
__global__ __launch_bounds__(256) void zero_kernel(float4* __restrict__ p) {
    p[(size_t)blockIdx.x * 256 + threadIdx.x] = make_float4(0.f, 0.f, 0.f, 0.f);
}

// ---------------------------------------------------------------------------
// Phase 1: KV[d][e] += sum_l Kf[l][d] * Vm[l][e]  ==  (Kf^T)(64xL) x Vm(Lx64)
// grid (64, NY), 256 thr, 8 tiles of 64 l-rows per block.
// Staging: thread owns a 4l x 4d block of K and V; packs 4 l-values per
// ds_write_b64 with an XOR swizzle on the l-offset so writes are
// bank-conflict-free and frag ds_read_b128 stay 16B-aligned.
// Double-buffered LDS + 1-deep register prefetch; no atomics on the main
// path (per-block partials -> reduce_kernel).
// ---------------------------------------------------------------------------
template<bool ATOMIC>
__global__ __launch_bounds__(256, 4) void kv_kernel2(
    const float* __restrict__ K, const float* __restrict__ V,
    const float* __restrict__ mask, const float* __restrict__ pi,
    const float* __restrict__ mu, float* __restrict__ kvout)
{
    __shared__ __align__(16) unsigned short sKs[2][64 * SLD];  // [d][l'] bf16
    __shared__ __align__(16) unsigned short sVs[2][64 * SLD];  // [e][l'] bf16
    __shared__ float muc[64];

    const int bh = blockIdx.x;
    const int b  = bh >> 4;
    const int h  = bh & 15;
    const int l0 = blockIdx.y * (L_ / NY);   // 512 rows per block
    const int t    = threadIdx.x;
    const int wave = t >> 6;
    const int lane = t & 63;
    const int r = lane & 15;      // MFMA m/n index
    const int q = lane >> 4;      // MFMA quad
    const int dchunk = t & 15;    // stages d-cols 4*dchunk .. +3
    const int lquad  = t >> 4;    // stages l-rows 4*lquad .. +3 (tile-local)

    const float p0 = fminf(fmaxf(pi[0], 0.f), 1.f);
    const float p1 = fminf(fmaxf(pi[1], 0.f), 1.f);
    const float psum = p0 + p1;
    if (t < 64) muc[t] = p0 * mu[h * 64 + t] + p1 * mu[1024 + h * 64 + t];

    const float* Kb = K + (size_t)bh * (L_ * 64) + (size_t)(l0 + 4 * lquad) * 64 + 4 * dchunk;
    const float* Vb = V + (size_t)bh * (L_ * 64) + (size_t)(l0 + 4 * lquad) * 64 + 4 * dchunk;
    const float* mb = mask + (size_t)b * L_ + l0 + 4 * lquad;

    // l-offset swizzle: element (d, l) lives at sX[d*SLD + (l ^ ((d>>2)&3)<<3)]
    const int loff = (4 * lquad) ^ ((dchunk & 3) << 3);  // write side (d>>2 == dchunk)
    const int swz  = ((r >> 2) & 3) << 3;                // read side (d = 16x + r)

    f32x4 acc[4];
#pragma unroll
    for (int i = 0; i < 4; ++i) acc[i] = (f32x4){0.f, 0.f, 0.f, 0.f};

    f32x4 ka[4], va[4], kb_[4], vb_[4];
    float ma_[4], mc_[4];

#define KV_LOAD(tt, KR, VR, MR)                                              \
    {                                                                        \
        _Pragma("unroll")                                                    \
        for (int i = 0; i < 4; ++i) {                                        \
            KR[i] = *(const f32x4*)(Kb + (size_t)((tt) * 64 + i) * 64);      \
            VR[i] = *(const f32x4*)(Vb + (size_t)((tt) * 64 + i) * 64);      \
            MR[i] = mb[(tt) * 64 + i];                                       \
        }                                                                    \
    }

#define KV_STAGE(KR, VR, MR, sKp, sVp)                                       \
    {                                                                        \
        const f32x4 mm = *(const f32x4*)&muc[4 * dchunk];                    \
        float s2_[4];                                                        \
        _Pragma("unroll")                                                    \
        for (int i = 0; i < 4; ++i) s2_[i] = SCALE * MR[i] * MR[i];          \
        _Pragma("unroll")                                                    \
        for (int j = 0; j < 4; ++j) {                                        \
            u16x4 wk, wv;                                                    \
            _Pragma("unroll")                                                \
            for (int i = 0; i < 4; ++i) {                                    \
                wk[i] = f2bf(elu1(KR[i][j] * psum - mm[j]) * s2_[i]);        \
                wv[i] = f2bf(VR[i][j]);                                      \
            }                                                                \
            *(u16x4*)&sKp[(4 * dchunk + j) * SLD + loff] = wk;               \
            *(u16x4*)&sVp[(4 * dchunk + j) * SLD + loff] = wv;               \
        }                                                                    \
    }

#define KV_MFMA(sKp, sVp)                                                    \
    {                                                                        \
        const int arow = (16 * wave + r) * SLD;                              \
        const bf16x8 a0 = *(const bf16x8*)&sKp[arow + ((8 * q) ^ swz)];      \
        const bf16x8 a1 = *(const bf16x8*)&sKp[arow + 32 + ((8 * q) ^ swz)]; \
        _Pragma("unroll")                                                    \
        for (int nt = 0; nt < 4; ++nt) {                                     \
            const int brow = (16 * nt + r) * SLD;                            \
            const bf16x8 b0 = *(const bf16x8*)&sVp[brow + ((8 * q) ^ swz)];  \
            const bf16x8 b1 = *(const bf16x8*)&sVp[brow + 32 + ((8 * q) ^ swz)]; \
            acc[nt] = __builtin_amdgcn_mfma_f32_16x16x32_bf16(a0, b0, acc[nt], 0, 0, 0); \
            acc[nt] = __builtin_amdgcn_mfma_f32_16x16x32_bf16(a1, b1, acc[nt], 0, 0, 0); \
        }                                                                    \
    }

    KV_LOAD(0, ka, va, ma_);
    __syncthreads();   // muc visible

#pragma unroll 1
    for (int t2 = 0; t2 < 8; t2 += 2) {
        KV_LOAD(t2 + 1, kb_, vb_, mc_);          // prefetch odd tile
        KV_STAGE(ka, va, ma_, sKs[0], sVs[0]);
        __syncthreads();
        KV_MFMA(sKs[0], sVs[0]);
        if (t2 + 2 < 8) { KV_LOAD(t2 + 2, ka, va, ma_); }  // prefetch next even tile
        KV_STAGE(kb_, vb_, mc_, sKs[1], sVs[1]);
        __syncthreads();
        KV_MFMA(sKs[1], sVs[1]);
    }

    if constexpr (ATOMIC) {
        float* kvb = kvout + (size_t)bh * 4096;
#pragma unroll
        for (int nt = 0; nt < 4; ++nt)
#pragma unroll
            for (int reg = 0; reg < 4; ++reg)
                atomicAdd(kvb + (16 * wave + 4 * q + reg) * 64 + 16 * nt + r, acc[nt][reg]);
    } else {
        float* pb = kvout + ((size_t)blockIdx.y * BH_ + bh) * 4096;
#pragma unroll
        for (int nt = 0; nt < 4; ++nt)
#pragma unroll
            for (int reg = 0; reg < 4; ++reg)
                pb[(16 * wave + 4 * q + reg) * 64 + 16 * nt + r] = acc[nt][reg];
    }
#undef KV_LOAD
#undef KV_STAGE
#undef KV_MFMA
}

// ---------------------------------------------------------------------------
// Reduce the NY partial KV panels -> final KV. grid (64, 4), 256 thr.
// Reads 16 MB coalesced, writes 1 MB.
// ---------------------------------------------------------------------------
__global__ __launch_bounds__(256) void reduce_kernel(
    const float* __restrict__ pb, float* __restrict__ kv)
{
    const int bh = blockIdx.x;
    const size_t idx = (size_t)blockIdx.y * 1024 + (size_t)threadIdx.x * 4;
    f32x4 s = (f32x4){0.f, 0.f, 0.f, 0.f};
#pragma unroll
    for (int y = 0; y < NY; ++y)
        s += *(const f32x4*)&pb[((size_t)y * BH_ + bh) * 4096 + idx];
    *(f32x4*)&kv[(size_t)bh * 4096 + idx] = s;
}

// ---------------------------------------------------------------------------
// Phase 2: out = Qf(Lx64) x KV(64x64) per bh.  (unchanged, verified)
// ---------------------------------------------------------------------------
__global__ __launch_bounds__(256) void out_kernel(
    const float* __restrict__ Q, const float* __restrict__ kv,
    float* __restrict__ out)
{
    __shared__ __align__(16) unsigned short sKVt[64 * SLD];  // [e][d] bf16

    const int bh = blockIdx.x;
    const int l0 = blockIdx.y * 512;
    const int t    = threadIdx.x;
    const int wave = t >> 6;
    const int lane = t & 63;
    const int r = lane & 15;
    const int q = lane >> 4;

    // stage KV transposed -> bf16 (one time)
    {
        const float* kvb = kv + (size_t)bh * 4096 + t * 16;
        const int d  = t >> 2;
        const int e0 = (t & 3) * 16;
#pragma unroll
        for (int j4 = 0; j4 < 4; ++j4) {
            const float4 f = *(const float4*)(kvb + 4 * j4);
            sKVt[(e0 + 4 * j4 + 0) * SLD + d] = f2bf(f.x);
            sKVt[(e0 + 4 * j4 + 1) * SLD + d] = f2bf(f.y);
            sKVt[(e0 + 4 * j4 + 2) * SLD + d] = f2bf(f.z);
            sKVt[(e0 + 4 * j4 + 3) * SLD + d] = f2bf(f.w);
        }
    }
    __syncthreads();

    // whole B operand in registers: B[k=d][n=e], frag = KV^T[16nt+r][32ks+8q+j]
    bf16x8 bfr[4][2];
#pragma unroll
    for (int nt = 0; nt < 4; ++nt) {
        bfr[nt][0] = *(const bf16x8*)&sKVt[(16 * nt + r) * SLD + 8 * q];
        bfr[nt][1] = *(const bf16x8*)&sKVt[(16 * nt + r) * SLD + 32 + 8 * q];
    }

    const int mbase = l0 + wave * 128;   // this wave's 128 rows
    const float* qrow = Q + (size_t)bh * (L_ * 64) + (size_t)(mbase + r) * 64 + 8 * q;
    float* ob = out + (size_t)bh * (L_ * 64);

    float4 c0 = *(const float4*)(qrow);
    float4 c1 = *(const float4*)(qrow + 4);
    float4 c2 = *(const float4*)(qrow + 32);
    float4 c3 = *(const float4*)(qrow + 36);

#pragma unroll 1
    for (int mt = 0; mt < 8; ++mt) {
        float4 n0, n1, n2, n3;
        if (mt < 7) {
            const float* nq = qrow + (size_t)(mt + 1) * 16 * 64;
            n0 = *(const float4*)(nq);
            n1 = *(const float4*)(nq + 4);
            n2 = *(const float4*)(nq + 32);
            n3 = *(const float4*)(nq + 36);
        }
        bf16x8 a0, a1;
        a0[0] = f2bf(elu1(c0.x) * SCALE); a0[1] = f2bf(elu1(c0.y) * SCALE);
        a0[2] = f2bf(elu1(c0.z) * SCALE); a0[3] = f2bf(elu1(c0.w) * SCALE);
        a0[4] = f2bf(elu1(c1.x) * SCALE); a0[5] = f2bf(elu1(c1.y) * SCALE);
        a0[6] = f2bf(elu1(c1.z) * SCALE); a0[7] = f2bf(elu1(c1.w) * SCALE);
        a1[0] = f2bf(elu1(c2.x) * SCALE); a1[1] = f2bf(elu1(c2.y) * SCALE);
        a1[2] = f2bf(elu1(c2.z) * SCALE); a1[3] = f2bf(elu1(c2.w) * SCALE);
        a1[4] = f2bf(elu1(c3.x) * SCALE); a1[5] = f2bf(elu1(c3.y) * SCALE);
        a1[6] = f2bf(elu1(c3.z) * SCALE); a1[7] = f2bf(elu1(c3.w) * SCALE);

        f32x4 acc[4];
#pragma unroll
        for (int nt = 0; nt < 4; ++nt) {
            acc[nt] = (f32x4){0.f, 0.f, 0.f, 0.f};
            acc[nt] = __builtin_amdgcn_mfma_f32_16x16x32_bf16(a0, bfr[nt][0], acc[nt], 0, 0, 0);
            acc[nt] = __builtin_amdgcn_mfma_f32_16x16x32_bf16(a1, bfr[nt][1], acc[nt], 0, 0, 0);
        }

        float* orow = ob + (size_t)(mbase + mt * 16 + 4 * q) * 64;
#pragma unroll
        for (int nt = 0; nt < 4; ++nt)
#pragma unroll
            for (int reg = 0; reg < 4; ++reg)
                orow[(size_t)reg * 64 + 16 * nt + r] = acc[nt][reg];

        c0 = n0; c1 = n1; c2 = n2; c3 = n3;
    }
}

extern "C" void kernel_launch(void* const* d_in, const int* in_sizes, int n_in,
                              void* d_out, int out_size, void* d_ws, size_t ws_size,
                              hipStream_t stream) {
    (void)in_sizes; (void)n_in; (void)out_size;
    const float* Q    = (const float*)d_in[0];
    const float* K    = (const float*)d_in[1];
    const float* V    = (const float*)d_in[2];
    const float* mask = (const float*)d_in[3];
    const float* pi   = (const float*)d_in[4];
    const float* mu   = (const float*)d_in[5];
    float* out = (float*)d_out;
    float* ws  = (float*)d_ws;

    const size_t part_floats = (size_t)NY * BH_ * 4096;            // 16 MiB of partials
    const size_t need_bytes  = (part_floats + (size_t)BH_ * 4096) * sizeof(float);

    if (ws_size >= need_bytes) {
        // main path: non-atomic partials + reduce
        float* pb  = ws;
        float* kvf = ws + part_floats;
        kv_kernel2<false><<<dim3(BH_, NY), 256, 0, stream>>>(K, V, mask, pi, mu, pb);
        reduce_kernel<<<dim3(BH_, 4), 256, 0, stream>>>(pb, kvf);
        out_kernel<<<dim3(BH_, 16), 256, 0, stream>>>(Q, kvf, out);
    } else {
        // fallback: atomic accumulation into a single 1 MiB KV buffer
        float* kvf = ws;
        zero_kernel<<<256, 256, 0, stream>>>((float4*)kvf);
        kv_kernel2<true><<<dim3(BH_, NY), 256, 0, stream>>>(K, V, mask, pi, mu, kvf);
        out_kernel<<<dim3(BH_, 16), 256, 0, stream>>>(Q, kvf, out);
    }
}